// Round 12
// baseline (35.091 us; speedup 1.0000x reference)
//
#include <hip/hip_runtime.h>

// TransformerBlockQuantum: B=16384, S=8, E=8, H=8 (dk=1), NW=8, FFN=512.
// R12: two specialized kernels.
// K1 tbq_front: 1 thread/token (R6 front, no max-sub in softmax), writes
//   hh (LN1 output, f32x8) into d_out used as scratch. 512 blocks x 256.
// K2 tbq_ffn: 32 tokens/wave (2 16x16 MFMA tiles), fragments register-
//   resident (gathered from f32 weights in prologue), zf recomputed from hh,
//   residual+LN2, overwrites d_out with final result. 4096 blocks x 64.
//   (K2 reads its own tokens' hh before overwriting them; blocks disjoint.)

typedef __fp16 half2v __attribute__((ext_vector_type(2)));
typedef __fp16 half4  __attribute__((ext_vector_type(4)));
typedef float  float4v __attribute__((ext_vector_type(4)));

#define SWZ(v, J) __int_as_float(__builtin_amdgcn_ds_swizzle(__float_as_int(v), ((J) << 5) | 0x18))
#define SWZ16(v) __int_as_float(__builtin_amdgcn_ds_swizzle(__float_as_int(v), (16 << 10) | 0x1F))

// ================= K1: front =================
__global__ __launch_bounds__(256) void tbq_front(
    const float* __restrict__ x,
    const float* __restrict__ ipw, const float* __restrict__ ipb,
    const float* __restrict__ opw, const float* __restrict__ opb,
    const float* __restrict__ rxa,
    const float* __restrict__ cw,  const float* __restrict__ cb,
    const float* __restrict__ g1,  const float* __restrict__ b1,
    float* __restrict__ hhout)
{
    const int tid  = blockIdx.x * 256 + threadIdx.x;
    const int base = tid * 8;

    float xr[8];
    {
        const float4* px = reinterpret_cast<const float4*>(x + base);
        float4 a = px[0], b = px[1];
        xr[0] = a.x; xr[1] = a.y; xr[2] = a.z; xr[3] = a.w;
        xr[4] = b.x; xr[5] = b.y; xr[6] = b.z; xr[7] = b.w;
    }

    float q[8], k[8], v[8];
    #pragma unroll
    for (int e = 0; e < 8; ++e) {
        float aq = ipb[e], ak = ipb[8 + e], av = ipb[16 + e];
        #pragma unroll
        for (int d = 0; d < 8; ++d) {
            aq = fmaf(xr[d], ipw[e * 8 + d],       aq);
            ak = fmaf(xr[d], ipw[64 + e * 8 + d],  ak);
            av = fmaf(xr[d], ipw[128 + e * 8 + d], av);
        }
        q[e] = aq; k[e] = ak; v[e] = av;
    }

    // attention, no max-subtraction (|scores| << 10, exp safe; softmax
    // is shift-invariant so result identical)
    float orow[8];
    #pragma unroll
    for (int h = 0; h < 8; ++h) {
        const float kh = k[h], vh = v[h], qh = q[h];
        float kk[8], vv[8];
        kk[0] = SWZ(kh, 0); kk[1] = SWZ(kh, 1); kk[2] = SWZ(kh, 2); kk[3] = SWZ(kh, 3);
        kk[4] = SWZ(kh, 4); kk[5] = SWZ(kh, 5); kk[6] = SWZ(kh, 6); kk[7] = SWZ(kh, 7);
        vv[0] = SWZ(vh, 0); vv[1] = SWZ(vh, 1); vv[2] = SWZ(vh, 2); vv[3] = SWZ(vh, 3);
        vv[4] = SWZ(vh, 4); vv[5] = SWZ(vh, 5); vv[6] = SWZ(vh, 6); vv[7] = SWZ(vh, 7);
        float p[8];
        #pragma unroll
        for (int j = 0; j < 8; ++j) p[j] = __expf(qh * kk[j]);
        float sum = ((p[0] + p[1]) + (p[2] + p[3])) + ((p[4] + p[5]) + (p[6] + p[7]));
        float ov = 0.f;
        #pragma unroll
        for (int j = 0; j < 8; ++j) ov = fmaf(p[j], vv[j], ov);
        orow[h] = ov * __builtin_amdgcn_rcpf(sum);
    }

    float ao[8];
    #pragma unroll
    for (int e = 0; e < 8; ++e) {
        float t = opb[e];
        #pragma unroll
        for (int h = 0; h < 8; ++h) t = fmaf(orow[h], opw[e * 8 + h], t);
        ao[e] = t;
    }

    float c[8];
    #pragma unroll
    for (int w = 0; w < 8; ++w) c[w] = __cosf(ao[w] + rxa[w]);
    float z[8];
    {
        float run = c[0];
        #pragma unroll
        for (int w = 1; w < 8; ++w) { run *= c[w]; z[w] = run; }
        float s17 = c[1];
        #pragma unroll
        for (int w = 2; w < 8; ++w) s17 *= c[w];
        z[0] = s17;
    }

    float saq[8];
    #pragma unroll
    for (int e = 0; e < 8; ++e) {
        float t = cb[e];
        #pragma unroll
        for (int w = 0; w < 8; ++w) t = fmaf(z[w], cw[e * 8 + w], t);
        saq[e] = ao[e] + t;
    }
    float at[8];
    #pragma unroll
    for (int e = 0; e < 8; ++e) {
        float t = cb[e];
        #pragma unroll
        for (int w = 0; w < 8; ++w) t = fmaf(saq[w], cw[e * 8 + w], t);
        at[e] = t;
    }

    float r[8]; float mean = 0.f;
    #pragma unroll
    for (int e = 0; e < 8; ++e) { r[e] = xr[e] + at[e]; mean += r[e]; }
    mean *= 0.125f;
    float var = 0.f;
    #pragma unroll
    for (int e = 0; e < 8; ++e) { float d = r[e] - mean; var = fmaf(d, d, var); }
    var *= 0.125f;
    float rs = __builtin_amdgcn_rsqf(var + 1e-5f);
    float hh[8];
    #pragma unroll
    for (int e = 0; e < 8; ++e) hh[e] = fmaf((r[e] - mean) * rs, g1[e], b1[e]);

    float4* ph = reinterpret_cast<float4*>(hhout + base);
    ph[0] = make_float4(hh[0], hh[1], hh[2], hh[3]);
    ph[1] = make_float4(hh[4], hh[5], hh[6], hh[7]);
}

// ================= K2: FFN + LN2 =================
// NOTE: hh and out alias (both = d_out). No __restrict__ on them.
__global__ __launch_bounds__(64) void tbq_ffn(
    const float* hh,
    const float* __restrict__ rxf,
    const float* __restrict__ l1w, const float* __restrict__ l1b,
    const float* __restrict__ l2w, const float* __restrict__ l2b,
    const float* __restrict__ g2,  const float* __restrict__ b2,
    float* out)
{
    const int l  = threadIdx.x;
    const int m  = l & 15;
    const int kg = (l >> 4) * 4;        // 0,4,8,12
    const int tok0 = blockIdx.x * 32;   // 2 tiles: tokens [tok0, tok0+32)

    // ---- load hh rows for bz build + epilogue (lanes 0-31 only) ----
    float4 h40 = make_float4(0.f, 0.f, 0.f, 0.f), h41 = h40;
    if (l < 32) {
        h40 = *reinterpret_cast<const float4*>(hh + (tok0 + m) * 8 + kg);
        h41 = *reinterpret_cast<const float4*>(hh + (tok0 + 16 + m) * 8 + kg);
    }

    // ---- gather MFMA A-fragments (L2-hot weights), register-resident ----
    // lane l holds A[m][k0+j]; A1: f=nf*16+m, k<8 -> W1[f][k], k==8 -> l1b[f].
    half4 a1[32], a2[32];
    const half4 zh = {(__fp16)0.f, (__fp16)0.f, (__fp16)0.f, (__fp16)0.f};
    if (l < 32) {
        #pragma unroll
        for (int nf = 0; nf < 32; ++nf) {
            float4 w = *reinterpret_cast<const float4*>(l1w + (nf * 16 + m) * 8 + kg);
            half2v c0 = __builtin_amdgcn_cvt_pkrtz(w.x, w.y);
            half2v c1 = __builtin_amdgcn_cvt_pkrtz(w.z, w.w);
            half4 rr; rr.x = c0.x; rr.y = c0.y; rr.z = c1.x; rr.w = c1.y;
            a1[nf] = rr;
        }
    } else if (l < 48) {
        #pragma unroll
        for (int nf = 0; nf < 32; ++nf) {
            half4 rr = zh; rr.x = (__fp16)l1b[nf * 16 + m];
            a1[nf] = rr;
        }
    } else {
        #pragma unroll
        for (int nf = 0; nf < 32; ++nf) a1[nf] = zh;
    }
    if (m < 8) {
        #pragma unroll
        for (int nf = 0; nf < 32; ++nf) {
            float4 w = *reinterpret_cast<const float4*>(l2w + m * 512 + nf * 16 + kg);
            half2v c0 = __builtin_amdgcn_cvt_pkrtz(w.x, w.y);
            half2v c1 = __builtin_amdgcn_cvt_pkrtz(w.z, w.w);
            half4 rr; rr.x = c0.x; rr.y = c0.y; rr.z = c1.x; rr.w = c1.y;
            a2[nf] = rr;
        }
    } else {
        #pragma unroll
        for (int nf = 0; nf < 32; ++nf) a2[nf] = zh;
    }

    // ---- bz fragments: zf = cos(hh + rxf), bias row k==8 = 1 ----
    half4 bz0 = zh, bz1 = zh;
    if (l < 32) {
        float4 rx4 = *reinterpret_cast<const float4*>(rxf + kg);
        float z00 = __cosf(h40.x + rx4.x), z01 = __cosf(h40.y + rx4.y);
        float z02 = __cosf(h40.z + rx4.z), z03 = __cosf(h40.w + rx4.w);
        float z10 = __cosf(h41.x + rx4.x), z11 = __cosf(h41.y + rx4.y);
        float z12 = __cosf(h41.z + rx4.z), z13 = __cosf(h41.w + rx4.w);
        half2v c0 = __builtin_amdgcn_cvt_pkrtz(z00, z01);
        half2v c1 = __builtin_amdgcn_cvt_pkrtz(z02, z03);
        bz0.x = c0.x; bz0.y = c0.y; bz0.z = c1.x; bz0.w = c1.y;
        half2v c2 = __builtin_amdgcn_cvt_pkrtz(z10, z11);
        half2v c3 = __builtin_amdgcn_cvt_pkrtz(z12, z13);
        bz1.x = c2.x; bz1.y = c2.y; bz1.z = c3.x; bz1.w = c3.y;
    } else if (l < 48) {
        bz0.x = (__fp16)1.f; bz1.x = (__fp16)1.f;
    }

    // ---- FFN loop: 2 tiles, 4 MFMA chains per iter ----
    const float4v zero4 = {0.f, 0.f, 0.f, 0.f};
    float4v acc0 = zero4, acc1 = zero4;
    #pragma unroll
    for (int nf = 0; nf < 32; ++nf) {
        float4v d0 = __builtin_amdgcn_mfma_f32_16x16x16f16(a1[nf], bz0, zero4, 0, 0, 0);
        float4v d1 = __builtin_amdgcn_mfma_f32_16x16x16f16(a1[nf], bz1, zero4, 0, 0, 0);
        d0.x = fmaxf(d0.x, 0.f); d0.y = fmaxf(d0.y, 0.f);
        d0.z = fmaxf(d0.z, 0.f); d0.w = fmaxf(d0.w, 0.f);
        d1.x = fmaxf(d1.x, 0.f); d1.y = fmaxf(d1.y, 0.f);
        d1.z = fmaxf(d1.z, 0.f); d1.w = fmaxf(d1.w, 0.f);
        half2v q00 = __builtin_amdgcn_cvt_pkrtz(d0.x, d0.y);
        half2v q01 = __builtin_amdgcn_cvt_pkrtz(d0.z, d0.w);
        half2v q10 = __builtin_amdgcn_cvt_pkrtz(d1.x, d1.y);
        half2v q11 = __builtin_amdgcn_cvt_pkrtz(d1.z, d1.w);
        half4 bu0; bu0.x = q00.x; bu0.y = q00.y; bu0.z = q01.x; bu0.w = q01.y;
        half4 bu1; bu1.x = q10.x; bu1.y = q10.y; bu1.z = q11.x; bu1.w = q11.y;
        acc0 = __builtin_amdgcn_mfma_f32_16x16x16f16(a2[nf], bu0, acc0, 0, 0, 0);
        acc1 = __builtin_amdgcn_mfma_f32_16x16x16f16(a2[nf], bu1, acc1, 0, 0, 0);
    }

    // ---- epilogue: residual + LN2 + store (lanes 0-31, both tiles) ----
    if (l < 32) {
        float4 lb4 = *reinterpret_cast<const float4*>(l2b + kg);
        float4 g4  = *reinterpret_cast<const float4*>(g2 + kg);
        float4 bb4 = *reinterpret_cast<const float4*>(b2 + kg);

        #pragma unroll
        for (int tt = 0; tt < 2; ++tt) {
            float4v acc = tt ? acc1 : acc0;
            float4 h4   = tt ? h41 : h40;
            float r2[4];
            r2[0] = h4.x + acc.x + lb4.x;
            r2[1] = h4.y + acc.y + lb4.y;
            r2[2] = h4.z + acc.z + lb4.z;
            r2[3] = h4.w + acc.w + lb4.w;
            float part = ((r2[0] + r2[1]) + (r2[2] + r2[3]));
            float mean2 = (part + SWZ16(part)) * 0.125f;
            float d0 = r2[0] - mean2, d1_ = r2[1] - mean2,
                  d2 = r2[2] - mean2, d3 = r2[3] - mean2;
            float vp = ((d0 * d0 + d1_ * d1_) + (d2 * d2 + d3 * d3));
            float rs2 = __builtin_amdgcn_rsqf((vp + SWZ16(vp)) * 0.125f + 1e-5f);
            float4 o;
            o.x = fmaf(d0 * rs2, g4.x, bb4.x);
            o.y = fmaf(d1_ * rs2, g4.y, bb4.y);
            o.z = fmaf(d2 * rs2, g4.z, bb4.z);
            o.w = fmaf(d3 * rs2, g4.w, bb4.w);
            *reinterpret_cast<float4*>(out + (tok0 + tt * 16 + m) * 8 + kg) = o;
        }
    }
}

extern "C" void kernel_launch(void* const* d_in, const int* in_sizes, int n_in,
                              void* d_out, int out_size, void* d_ws, size_t ws_size,
                              hipStream_t stream) {
    const float* x   = (const float*)d_in[0];
    const float* ipw = (const float*)d_in[1];
    const float* ipb = (const float*)d_in[2];
    const float* opw = (const float*)d_in[3];
    const float* opb = (const float*)d_in[4];
    const float* rxa = (const float*)d_in[5];
    const float* cw  = (const float*)d_in[6];
    const float* cb  = (const float*)d_in[7];
    const float* g1  = (const float*)d_in[8];
    const float* b1  = (const float*)d_in[9];
    const float* rxf = (const float*)d_in[10];
    const float* l1w = (const float*)d_in[11];
    const float* l1b = (const float*)d_in[12];
    const float* l2w = (const float*)d_in[13];
    const float* l2b = (const float*)d_in[14];
    const float* g2  = (const float*)d_in[15];
    const float* b2  = (const float*)d_in[16];
    float* out = (float*)d_out;

    const int tokens = 16384 * 8;   // 131072

    // K1: front -> hh written into d_out (scratch), 512 blocks x 256
    tbq_front<<<dim3(tokens / 256), dim3(256), 0, stream>>>(
        x, ipw, ipb, opw, opb, rxa, cw, cb, g1, b1, out);

    // K2: FFN + LN2, reads hh from d_out then overwrites with final result.
    // Each block reads only its own 32 tokens before writing them.
    tbq_ffn<<<dim3(tokens / 32), dim3(64), 0, stream>>>(
        out, rxf, l1w, l1b, l2w, l2b, g2, b2, out);
}

// Round 13
// 22.827 us; speedup vs baseline: 1.5373x; 1.5373x over previous
//
#include <hip/hip_runtime.h>

// TransformerBlockQuantum: B=16384, S=8, E=8, H=8 (dk=1), NW=8, FFN=512.
// R13: two kernels, gather fixed.
// K1 tbq_front: 1 thread/token front (no max-sub softmax), writes hh into
//   d_out (scratch). Blocks 0-15 ALSO prepack MFMA fragments into d_ws
//   (a1: W1+bias row, a2: W2) - no separate pack launch.
// K2 tbq_ffn: 256 thr = 4 waves; block stages the 32KB prepacked fragments
//   into LDS cooperatively; each wave = one 32-token tile-pair; MFMA loop
//   reads fragments via ds_read_b64 (conflict-free); residual+LN2+store.

typedef __fp16 half2v __attribute__((ext_vector_type(2)));
typedef __fp16 half4  __attribute__((ext_vector_type(4)));
typedef float  float4v __attribute__((ext_vector_type(4)));

#define SWZ(v, J) __int_as_float(__builtin_amdgcn_ds_swizzle(__float_as_int(v), ((J) << 5) | 0x18))
#define SWZ16(v) __int_as_float(__builtin_amdgcn_ds_swizzle(__float_as_int(v), (16 << 10) | 0x1F))

// ================= K1: front (+ fragment pack in blocks 0-15) =================
__global__ __launch_bounds__(256) void tbq_front(
    const float* __restrict__ x,
    const float* __restrict__ ipw, const float* __restrict__ ipb,
    const float* __restrict__ opw, const float* __restrict__ opb,
    const float* __restrict__ rxa,
    const float* __restrict__ cw,  const float* __restrict__ cb,
    const float* __restrict__ g1,  const float* __restrict__ b1,
    const float* __restrict__ l1w, const float* __restrict__ l1b,
    const float* __restrict__ l2w,
    half4* __restrict__ a1ws, half4* __restrict__ a2ws,
    float* __restrict__ hhout)
{
    // ---- fragment pack (blocks 0-15; 4096 threads cover both arrays) ----
    if (blockIdx.x < 16) {
        int t = blockIdx.x * 256 + threadIdx.x;   // 0..4095
        int u = t & 2047;
        int nf = u >> 6, ll = u & 63;
        int mm = ll & 15, kk0 = (ll >> 4) * 4;
        half4 r;
        if (t < 2048) {
            int f = nf * 16 + mm;
            #pragma unroll
            for (int j = 0; j < 4; ++j) {
                int k = kk0 + j;
                float v = (k < 8) ? l1w[f * 8 + k] : ((k == 8) ? l1b[f] : 0.f);
                r[j] = (__fp16)v;
            }
            a1ws[nf * 64 + ll] = r;
        } else {
            #pragma unroll
            for (int j = 0; j < 4; ++j) {
                int k = kk0 + j;
                float v = (mm < 8) ? l2w[mm * 512 + nf * 16 + k] : 0.f;
                r[j] = (__fp16)v;
            }
            a2ws[nf * 64 + ll] = r;
        }
    }

    const int tid  = blockIdx.x * 256 + threadIdx.x;
    const int base = tid * 8;

    float xr[8];
    {
        const float4* px = reinterpret_cast<const float4*>(x + base);
        float4 a = px[0], b = px[1];
        xr[0] = a.x; xr[1] = a.y; xr[2] = a.z; xr[3] = a.w;
        xr[4] = b.x; xr[5] = b.y; xr[6] = b.z; xr[7] = b.w;
    }

    float q[8], k[8], v[8];
    #pragma unroll
    for (int e = 0; e < 8; ++e) {
        float aq = ipb[e], ak = ipb[8 + e], av = ipb[16 + e];
        #pragma unroll
        for (int d = 0; d < 8; ++d) {
            aq = fmaf(xr[d], ipw[e * 8 + d],       aq);
            ak = fmaf(xr[d], ipw[64 + e * 8 + d],  ak);
            av = fmaf(xr[d], ipw[128 + e * 8 + d], av);
        }
        q[e] = aq; k[e] = ak; v[e] = av;
    }

    // attention; softmax without max-subtraction (shift-invariant, |s| small)
    float orow[8];
    #pragma unroll
    for (int h = 0; h < 8; ++h) {
        const float kh = k[h], vh = v[h], qh = q[h];
        float kk[8], vv[8];
        kk[0] = SWZ(kh, 0); kk[1] = SWZ(kh, 1); kk[2] = SWZ(kh, 2); kk[3] = SWZ(kh, 3);
        kk[4] = SWZ(kh, 4); kk[5] = SWZ(kh, 5); kk[6] = SWZ(kh, 6); kk[7] = SWZ(kh, 7);
        vv[0] = SWZ(vh, 0); vv[1] = SWZ(vh, 1); vv[2] = SWZ(vh, 2); vv[3] = SWZ(vh, 3);
        vv[4] = SWZ(vh, 4); vv[5] = SWZ(vh, 5); vv[6] = SWZ(vh, 6); vv[7] = SWZ(vh, 7);
        float p[8];
        #pragma unroll
        for (int j = 0; j < 8; ++j) p[j] = __expf(qh * kk[j]);
        float sum = ((p[0] + p[1]) + (p[2] + p[3])) + ((p[4] + p[5]) + (p[6] + p[7]));
        float ov = 0.f;
        #pragma unroll
        for (int j = 0; j < 8; ++j) ov = fmaf(p[j], vv[j], ov);
        orow[h] = ov * __builtin_amdgcn_rcpf(sum);
    }

    float ao[8];
    #pragma unroll
    for (int e = 0; e < 8; ++e) {
        float t = opb[e];
        #pragma unroll
        for (int h = 0; h < 8; ++h) t = fmaf(orow[h], opw[e * 8 + h], t);
        ao[e] = t;
    }

    float c[8];
    #pragma unroll
    for (int w = 0; w < 8; ++w) c[w] = __cosf(ao[w] + rxa[w]);
    float z[8];
    {
        float run = c[0];
        #pragma unroll
        for (int w = 1; w < 8; ++w) { run *= c[w]; z[w] = run; }
        float s17 = c[1];
        #pragma unroll
        for (int w = 2; w < 8; ++w) s17 *= c[w];
        z[0] = s17;
    }

    float saq[8];
    #pragma unroll
    for (int e = 0; e < 8; ++e) {
        float t = cb[e];
        #pragma unroll
        for (int w = 0; w < 8; ++w) t = fmaf(z[w], cw[e * 8 + w], t);
        saq[e] = ao[e] + t;
    }
    float at[8];
    #pragma unroll
    for (int e = 0; e < 8; ++e) {
        float t = cb[e];
        #pragma unroll
        for (int w = 0; w < 8; ++w) t = fmaf(saq[w], cw[e * 8 + w], t);
        at[e] = t;
    }

    float r[8]; float mean = 0.f;
    #pragma unroll
    for (int e = 0; e < 8; ++e) { r[e] = xr[e] + at[e]; mean += r[e]; }
    mean *= 0.125f;
    float var = 0.f;
    #pragma unroll
    for (int e = 0; e < 8; ++e) { float d = r[e] - mean; var = fmaf(d, d, var); }
    var *= 0.125f;
    float rs = __builtin_amdgcn_rsqf(var + 1e-5f);
    float hh[8];
    #pragma unroll
    for (int e = 0; e < 8; ++e) hh[e] = fmaf((r[e] - mean) * rs, g1[e], b1[e]);

    float4* ph = reinterpret_cast<float4*>(hhout + base);
    ph[0] = make_float4(hh[0], hh[1], hh[2], hh[3]);
    ph[1] = make_float4(hh[4], hh[5], hh[6], hh[7]);
}

// ================= K2: FFN + LN2 (LDS-staged fragments) =================
// hh and out alias (both = d_out): no __restrict__ on them.
__global__ __launch_bounds__(256) void tbq_ffn(
    const float* hh,
    const float* __restrict__ rxf,
    const half4* __restrict__ a1ws, const half4* __restrict__ a2ws,
    const float* __restrict__ l2b,
    const float* __restrict__ g2,  const float* __restrict__ b2,
    float* out)
{
    __shared__ half4 a1l[2048];     // 16KB
    __shared__ half4 a2l[2048];     // 16KB

    const int tid = threadIdx.x;
    const int l   = tid & 63;
    const int wv  = tid >> 6;

    // ---- cooperative stage of prepacked fragments into LDS ----
    {
        const uint4* s1 = reinterpret_cast<const uint4*>(a1ws);
        const uint4* s2 = reinterpret_cast<const uint4*>(a2ws);
        uint4* t1 = reinterpret_cast<uint4*>(a1l);
        uint4* t2 = reinterpret_cast<uint4*>(a2l);
        #pragma unroll
        for (int i = 0; i < 4; ++i) {
            t1[tid + i * 256] = s1[tid + i * 256];
            t2[tid + i * 256] = s2[tid + i * 256];
        }
    }

    const int m  = l & 15;
    const int kg = (l >> 4) * 4;                    // 0,4,8,12
    const int tok0 = blockIdx.x * 128 + wv * 32;    // this wave's 32 tokens

    // ---- hh rows for bz build + epilogue (lanes 0-31) ----
    float4 h40 = make_float4(0.f, 0.f, 0.f, 0.f), h41 = h40;
    if (l < 32) {
        h40 = *reinterpret_cast<const float4*>(hh + (tok0 + m) * 8 + kg);
        h41 = *reinterpret_cast<const float4*>(hh + (tok0 + 16 + m) * 8 + kg);
    }

    // ---- bz fragments: zf = cos(hh + rxf); bias row k==8 = 1 ----
    const half4 zh = {(__fp16)0.f, (__fp16)0.f, (__fp16)0.f, (__fp16)0.f};
    half4 bz0 = zh, bz1 = zh;
    if (l < 32) {
        float4 rx4 = *reinterpret_cast<const float4*>(rxf + kg);
        float z00 = __cosf(h40.x + rx4.x), z01 = __cosf(h40.y + rx4.y);
        float z02 = __cosf(h40.z + rx4.z), z03 = __cosf(h40.w + rx4.w);
        float z10 = __cosf(h41.x + rx4.x), z11 = __cosf(h41.y + rx4.y);
        float z12 = __cosf(h41.z + rx4.z), z13 = __cosf(h41.w + rx4.w);
        half2v c0 = __builtin_amdgcn_cvt_pkrtz(z00, z01);
        half2v c1 = __builtin_amdgcn_cvt_pkrtz(z02, z03);
        bz0.x = c0.x; bz0.y = c0.y; bz0.z = c1.x; bz0.w = c1.y;
        half2v c2 = __builtin_amdgcn_cvt_pkrtz(z10, z11);
        half2v c3 = __builtin_amdgcn_cvt_pkrtz(z12, z13);
        bz1.x = c2.x; bz1.y = c2.y; bz1.z = c3.x; bz1.w = c3.y;
    } else if (l < 48) {
        bz0.x = (__fp16)1.f; bz1.x = (__fp16)1.f;
    }

    __syncthreads();

    // ---- FFN loop: fragments from LDS, 4 MFMA chains/iter ----
    const float4v zero4 = {0.f, 0.f, 0.f, 0.f};
    float4v acc0 = zero4, acc1 = zero4;
    #pragma unroll
    for (int nf = 0; nf < 32; ++nf) {
        half4 a1f = a1l[nf * 64 + l];
        half4 a2f = a2l[nf * 64 + l];
        float4v d0 = __builtin_amdgcn_mfma_f32_16x16x16f16(a1f, bz0, zero4, 0, 0, 0);
        float4v d1 = __builtin_amdgcn_mfma_f32_16x16x16f16(a1f, bz1, zero4, 0, 0, 0);
        d0.x = fmaxf(d0.x, 0.f); d0.y = fmaxf(d0.y, 0.f);
        d0.z = fmaxf(d0.z, 0.f); d0.w = fmaxf(d0.w, 0.f);
        d1.x = fmaxf(d1.x, 0.f); d1.y = fmaxf(d1.y, 0.f);
        d1.z = fmaxf(d1.z, 0.f); d1.w = fmaxf(d1.w, 0.f);
        half2v q00 = __builtin_amdgcn_cvt_pkrtz(d0.x, d0.y);
        half2v q01 = __builtin_amdgcn_cvt_pkrtz(d0.z, d0.w);
        half2v q10 = __builtin_amdgcn_cvt_pkrtz(d1.x, d1.y);
        half2v q11 = __builtin_amdgcn_cvt_pkrtz(d1.z, d1.w);
        half4 bu0; bu0.x = q00.x; bu0.y = q00.y; bu0.z = q01.x; bu0.w = q01.y;
        half4 bu1; bu1.x = q10.x; bu1.y = q10.y; bu1.z = q11.x; bu1.w = q11.y;
        acc0 = __builtin_amdgcn_mfma_f32_16x16x16f16(a2f, bu0, acc0, 0, 0, 0);
        acc1 = __builtin_amdgcn_mfma_f32_16x16x16f16(a2f, bu1, acc1, 0, 0, 0);
    }

    // ---- epilogue: residual + LN2 + store (lanes 0-31, both tiles) ----
    if (l < 32) {
        float4 lb4 = *reinterpret_cast<const float4*>(l2b + kg);
        float4 g4  = *reinterpret_cast<const float4*>(g2 + kg);
        float4 bb4 = *reinterpret_cast<const float4*>(b2 + kg);

        #pragma unroll
        for (int tt = 0; tt < 2; ++tt) {
            float4v acc = tt ? acc1 : acc0;
            float4 h4   = tt ? h41 : h40;
            float r2[4];
            r2[0] = h4.x + acc.x + lb4.x;
            r2[1] = h4.y + acc.y + lb4.y;
            r2[2] = h4.z + acc.z + lb4.z;
            r2[3] = h4.w + acc.w + lb4.w;
            float part = ((r2[0] + r2[1]) + (r2[2] + r2[3]));
            float mean2 = (part + SWZ16(part)) * 0.125f;
            float d0 = r2[0] - mean2, d1_ = r2[1] - mean2,
                  d2 = r2[2] - mean2, d3 = r2[3] - mean2;
            float vp = ((d0 * d0 + d1_ * d1_) + (d2 * d2 + d3 * d3));
            float rs2 = __builtin_amdgcn_rsqf((vp + SWZ16(vp)) * 0.125f + 1e-5f);
            float4 o;
            o.x = fmaf(d0 * rs2, g4.x, bb4.x);
            o.y = fmaf(d1_ * rs2, g4.y, bb4.y);
            o.z = fmaf(d2 * rs2, g4.z, bb4.z);
            o.w = fmaf(d3 * rs2, g4.w, bb4.w);
            *reinterpret_cast<float4*>(out + (tok0 + tt * 16 + m) * 8 + kg) = o;
        }
    }
}

extern "C" void kernel_launch(void* const* d_in, const int* in_sizes, int n_in,
                              void* d_out, int out_size, void* d_ws, size_t ws_size,
                              hipStream_t stream) {
    const float* x   = (const float*)d_in[0];
    const float* ipw = (const float*)d_in[1];
    const float* ipb = (const float*)d_in[2];
    const float* opw = (const float*)d_in[3];
    const float* opb = (const float*)d_in[4];
    const float* rxa = (const float*)d_in[5];
    const float* cw  = (const float*)d_in[6];
    const float* cb  = (const float*)d_in[7];
    const float* g1  = (const float*)d_in[8];
    const float* b1  = (const float*)d_in[9];
    const float* rxf = (const float*)d_in[10];
    const float* l1w = (const float*)d_in[11];
    const float* l1b = (const float*)d_in[12];
    const float* l2w = (const float*)d_in[13];
    const float* l2b = (const float*)d_in[14];
    const float* g2  = (const float*)d_in[15];
    const float* b2  = (const float*)d_in[16];
    float* out = (float*)d_out;

    half4* a1ws = (half4*)d_ws;                    // 16KB
    half4* a2ws = (half4*)((char*)d_ws + 16384);   // 16KB

    const int tokens = 16384 * 8;   // 131072

    // K1: front (blocks 0-15 also pack fragments into d_ws)
    tbq_front<<<dim3(tokens / 256), dim3(256), 0, stream>>>(
        x, ipw, ipb, opw, opb, rxa, cw, cb, g1, b1,
        l1w, l1b, l2w, a1ws, a2ws, out);

    // K2: FFN + LN2; 4 waves/block, LDS-staged fragments
    tbq_ffn<<<dim3(tokens / 128), dim3(256), 0, stream>>>(
        out, rxf, a1ws, a2ws, l2b, g2, b2, out);
}